// Round 1
// baseline (354.812 us; speedup 1.0000x reference)
//
#include <hip/hip_runtime.h>
#include <hip/hip_bf16.h>

// GAT layer, N=4096 nodes, FIN=512, H=4 heads, F=64.
// Round 1: fully-f32 correct baseline.
//   K1: XW = X @ W            (tiled f32 GEMM, 64x64 tile, TK=16)
//   K2: f1t[n][h], f2t[n][h]  (score projections, [n][4] layout for float4)
//   K3: fused masked-softmax attention, NO max subtraction (scores bounded,
//       exp<=e^9 fits f32; softmax identical). One block = 8 rows, wave h =
//       head h. Per 64-j chunk: 256 threads compute p -> LDS (l-sum as
//       by-product), then wave h lane f accumulates acc[r] += p*XW[j,h,f]
//       (p read is lane-uniform ds_read_b128 broadcast; XW read coalesced).

#define NN   4096
#define FIN  512
#define H    4
#define F    64
#define HF   256   // H*F

// ---------------- K1: GEMM ----------------
#define TM 64
#define TN 64
#define TK 16

__global__ __launch_bounds__(256) void gemm_xw(const float* __restrict__ X,
                                               const float* __restrict__ W,
                                               float* __restrict__ XW) {
    __shared__ float Ast[TK][TM];   // A tile transposed: [k][m]
    __shared__ float Bs[TK][TN];    // B tile: [k][n]
    const int bi = blockIdx.x;      // 0..63  (row tile)
    const int bj = blockIdx.y;      // 0..3   (col tile)
    const int t  = threadIdx.x;
    const int tx = t & 15, ty = t >> 4;

    float acc[4][4];
#pragma unroll
    for (int a = 0; a < 4; ++a)
#pragma unroll
        for (int b = 0; b < 4; ++b) acc[a][b] = 0.f;

    // A load mapping: row r = t>>2 (0..63), 4 consecutive k at (t&3)*4
    const int ar = t >> 2, ac4 = (t & 3) * 4;
    // B load mapping: k = t>>4 (0..15), 4 consecutive n at (t&15)*4
    const int bk = t >> 4, bn4 = (t & 15) * 4;

    const float* Arow = X + (bi * TM + ar) * FIN + ac4;
    const float* Brow = W + bk * HF + bj * TN + bn4;

    for (int k0 = 0; k0 < FIN; k0 += TK) {
        float4 av = *(const float4*)(Arow + k0);
        float4 bv = *(const float4*)(Brow + k0 * HF);
        __syncthreads();           // previous iteration's reads complete
        Ast[ac4 + 0][ar] = av.x;
        Ast[ac4 + 1][ar] = av.y;
        Ast[ac4 + 2][ar] = av.z;
        Ast[ac4 + 3][ar] = av.w;
        *(float4*)&Bs[bk][bn4] = bv;
        __syncthreads();
#pragma unroll
        for (int k = 0; k < TK; ++k) {
            float4 a4 = *(const float4*)&Ast[k][ty * 4];
            float4 b4 = *(const float4*)&Bs[k][tx * 4];
            acc[0][0] += a4.x * b4.x; acc[0][1] += a4.x * b4.y;
            acc[0][2] += a4.x * b4.z; acc[0][3] += a4.x * b4.w;
            acc[1][0] += a4.y * b4.x; acc[1][1] += a4.y * b4.y;
            acc[1][2] += a4.y * b4.z; acc[1][3] += a4.y * b4.w;
            acc[2][0] += a4.z * b4.x; acc[2][1] += a4.z * b4.y;
            acc[2][2] += a4.z * b4.z; acc[2][3] += a4.z * b4.w;
            acc[3][0] += a4.w * b4.x; acc[3][1] += a4.w * b4.y;
            acc[3][2] += a4.w * b4.z; acc[3][3] += a4.w * b4.w;
        }
    }
#pragma unroll
    for (int r = 0; r < 4; ++r) {
        float4 o = make_float4(acc[r][0], acc[r][1], acc[r][2], acc[r][3]);
        *(float4*)&XW[(bi * TM + ty * 4 + r) * HF + bj * TN + tx * 4] = o;
    }
}

// ---------------- K2: score projections ----------------
// f1t[n*4+h] = dot(XW[n,h,:], a_src[h,:]);  f2t likewise with a_dst.
__global__ __launch_bounds__(256) void scores_kernel(const float* __restrict__ XW,
                                                     const float* __restrict__ a_src,
                                                     const float* __restrict__ a_dst,
                                                     float* __restrict__ f1t,
                                                     float* __restrict__ f2t) {
    int gid = blockIdx.x * 256 + threadIdx.x;   // 0..16383
    int n = gid >> 2, h = gid & 3;
    const float* row = XW + n * HF + h * F;
    const float* as  = a_src + h * F;
    const float* ad  = a_dst + h * F;
    float s1 = 0.f, s2 = 0.f;
#pragma unroll
    for (int k = 0; k < F; k += 4) {
        float4 v  = *(const float4*)(row + k);
        float4 w1 = *(const float4*)(as + k);
        float4 w2 = *(const float4*)(ad + k);
        s1 += v.x * w1.x + v.y * w1.y + v.z * w1.z + v.w * w1.w;
        s2 += v.x * w2.x + v.y * w2.y + v.z * w2.z + v.w * w2.w;
    }
    f1t[gid] = s1;
    f2t[gid] = s2;
}

// ---------------- K3: fused masked softmax-attention ----------------
#define RROWS 8
#define JC    64
#define PSTR  12   // p_lds inner stride (floats): 16B-aligned, limits write
                   // conflicts to 8-way on 2 instrs/chunk (amortized ~4%)

__global__ __launch_bounds__(256) void gat_attn(const int*  __restrict__ A,
                                                const float* __restrict__ XW,
                                                const float* __restrict__ f1t,
                                                const float* __restrict__ f2t,
                                                float* __restrict__ out) {
    __shared__ float p_lds[H * JC * PSTR];   // [h][jl][r], 12KB
    const int i0   = blockIdx.x * RROWS;
    const int t    = threadIdx.x;
    const int h    = t >> 6;     // wave id == head
    const int lane = t & 63;     // jl in p-phase, f in acc-phase

    float c[RROWS];
#pragma unroll
    for (int r = 0; r < RROWS; ++r) c[r] = f1t[(i0 + r) * 4 + h];

    float acc[RROWS], lsum[RROWS];
#pragma unroll
    for (int r = 0; r < RROWS; ++r) { acc[r] = 0.f; lsum[r] = 0.f; }

    float* pme = &p_lds[(h * JC + lane) * PSTR];

    for (int jc = 0; jc < NN; jc += JC) {
        const int j = jc + lane;
        const float g = f2t[j * 4 + h];
        float pv[RROWS];
#pragma unroll
        for (int r = 0; r < RROWS; ++r) {
            int a = A[(i0 + r) * NN + j];
            float s = c[r] + g;
            s = fmaxf(s, 0.2f * s);              // leaky relu
            float p = (a != 0) ? __expf(s) : 0.f; // no max-sub needed (bounded)
            pv[r] = p;
            lsum[r] += p;
        }
        __syncthreads();   // previous chunk fully consumed
        *(float4*)(pme + 0) = make_float4(pv[0], pv[1], pv[2], pv[3]);
        *(float4*)(pme + 4) = make_float4(pv[4], pv[5], pv[6], pv[7]);
        __syncthreads();

        const float* xwp = XW + jc * HF + h * F + lane;   // coalesced over lane
        const float* pl  = &p_lds[h * JC * PSTR];
#pragma unroll 4
        for (int jl = 0; jl < JC; ++jl) {
            float v = xwp[jl * HF];
            const float* pp = pl + jl * PSTR;             // lane-uniform: broadcast
            float4 plo = *(const float4*)(pp);
            float4 phi = *(const float4*)(pp + 4);
            acc[0] += plo.x * v; acc[1] += plo.y * v;
            acc[2] += plo.z * v; acc[3] += plo.w * v;
            acc[4] += phi.x * v; acc[5] += phi.y * v;
            acc[6] += phi.z * v; acc[7] += phi.w * v;
        }
    }

    // reduce l over the 64 lanes of this wave (each lane summed its jl slice)
#pragma unroll
    for (int r = 0; r < RROWS; ++r) {
        float l = lsum[r];
#pragma unroll
        for (int off = 1; off < 64; off <<= 1) l += __shfl_xor(l, off, 64);
        lsum[r] = l;
    }

    const int f = lane;
#pragma unroll
    for (int r = 0; r < RROWS; ++r) {
        float a = acc[r];
        float l = lsum[r];
        if (l == 0.f) {   // empty row: reference softmax degenerates to uniform
            float s = 0.f;
            for (int j = 0; j < NN; ++j) s += XW[j * HF + h * F + f];
            a = s; l = (float)NN;
        }
        float o = a / l;
        o = (o > 0.f) ? o : (__expf(o) - 1.0f);   // elu(alpha=1)
        out[(i0 + r) * HF + h * F + f] = o;
    }
}

// ---------------- launch ----------------
extern "C" void kernel_launch(void* const* d_in, const int* in_sizes, int n_in,
                              void* d_out, int out_size, void* d_ws, size_t ws_size,
                              hipStream_t stream) {
    const float* X     = (const float*)d_in[0];
    const int*   A     = (const int*)d_in[1];
    const float* W     = (const float*)d_in[2];
    const float* a_src = (const float*)d_in[3];
    const float* a_dst = (const float*)d_in[4];
    float* out = (float*)d_out;

    // workspace: XW (4 MB) | f1t (64 KB) | f2t (64 KB)
    float* XW  = (float*)d_ws;
    float* f1t = XW + NN * HF;
    float* f2t = f1t + NN * H;

    gemm_xw<<<dim3(64, 4), 256, 0, stream>>>(X, W, XW);
    scores_kernel<<<64, 256, 0, stream>>>(XW, a_src, a_dst, f1t, f2t);
    gat_attn<<<NN / RROWS, 256, 0, stream>>>(A, XW, f1t, f2t, out);
}

// Round 3
// 138.569 us; speedup vs baseline: 2.5605x; 2.5605x over previous
//
#include <hip/hip_runtime.h>
#include <hip/hip_bf16.h>

// GAT layer, N=4096, FIN=512, H=4 heads, F=64.
// R3: fixes R2's partial-write race (waves now own HEADS, not j-strips) and
// adds split-precision bf16 PV (p=p_hi+p_lo, v=v_hi+v_lo; hi*hi+hi*lo+lo*hi).
//   K1: XW = X @ W (f32 tiled GEMM)
//   K2: f1h/f2h = score projections x log2e, layout [H][N];
//       XWbT hi/lo = bf16-split transpose [HF][N]
//   K3: grid (128 row-blocks x 4 j-blocks), 4 waves = 4 heads, 32 rows/block.
//       P built directly in MFMA A-fragment layout; PV + ones-rowsum MFMAs.
//       No max-subtraction (scores bounded ~|10| -> exp fits f32; softmax
//       identical). No LDS, no syncthreads.
//   K4: combine 4 j-partials, normalize, ELU.
// ws: pacc(16MB, aliases XW) | f1h | f2h | XWbT_hi(2MB) | XWbT_lo(2MB) | plsum

#define NN   4096
#define FIN  512
#define H    4
#define F    64
#define HF   256
#define LOG2E 1.44269504088896340736f

typedef __attribute__((ext_vector_type(4))) float f32x4;
typedef __attribute__((ext_vector_type(8))) short short8;

// ---------------- K1: GEMM (f32) ----------------
#define TM 64
#define TN 64
#define TK 16

__global__ __launch_bounds__(256) void gemm_xw(const float* __restrict__ X,
                                               const float* __restrict__ W,
                                               float* __restrict__ XW) {
    __shared__ float Ast[TK][TM];
    __shared__ float Bs[TK][TN];
    const int bi = blockIdx.x;
    const int bj = blockIdx.y;
    const int t  = threadIdx.x;
    const int tx = t & 15, ty = t >> 4;

    float acc[4][4];
#pragma unroll
    for (int a = 0; a < 4; ++a)
#pragma unroll
        for (int b = 0; b < 4; ++b) acc[a][b] = 0.f;

    const int ar = t >> 2, ac4 = (t & 3) * 4;
    const int bk = t >> 4, bn4 = (t & 15) * 4;

    const float* Arow = X + (bi * TM + ar) * FIN + ac4;
    const float* Brow = W + bk * HF + bj * TN + bn4;

    for (int k0 = 0; k0 < FIN; k0 += TK) {
        float4 av = *(const float4*)(Arow + k0);
        float4 bv = *(const float4*)(Brow + k0 * HF);
        __syncthreads();
        Ast[ac4 + 0][ar] = av.x;
        Ast[ac4 + 1][ar] = av.y;
        Ast[ac4 + 2][ar] = av.z;
        Ast[ac4 + 3][ar] = av.w;
        *(float4*)&Bs[bk][bn4] = bv;
        __syncthreads();
#pragma unroll
        for (int k = 0; k < TK; ++k) {
            float4 a4 = *(const float4*)&Ast[k][ty * 4];
            float4 b4 = *(const float4*)&Bs[k][tx * 4];
            acc[0][0] += a4.x * b4.x; acc[0][1] += a4.x * b4.y;
            acc[0][2] += a4.x * b4.z; acc[0][3] += a4.x * b4.w;
            acc[1][0] += a4.y * b4.x; acc[1][1] += a4.y * b4.y;
            acc[1][2] += a4.y * b4.z; acc[1][3] += a4.y * b4.w;
            acc[2][0] += a4.z * b4.x; acc[2][1] += a4.z * b4.y;
            acc[2][2] += a4.z * b4.z; acc[2][3] += a4.z * b4.w;
            acc[3][0] += a4.w * b4.x; acc[3][1] += a4.w * b4.y;
            acc[3][2] += a4.w * b4.z; acc[3][3] += a4.w * b4.w;
        }
    }
#pragma unroll
    for (int r = 0; r < 4; ++r) {
        float4 o = make_float4(acc[r][0], acc[r][1], acc[r][2], acc[r][3]);
        *(float4*)&XW[(bi * TM + ty * 4 + r) * HF + bj * TN + tx * 4] = o;
    }
}

// ---------------- K2: scores (x log2e, [H][N]) + bf16-split transpose --------
__global__ __launch_bounds__(256) void scores_transpose(
        const float* __restrict__ XW, const float* __restrict__ a_src,
        const float* __restrict__ a_dst, float* __restrict__ f1h,
        float* __restrict__ f2h, __hip_bfloat16* __restrict__ Vhi,
        __hip_bfloat16* __restrict__ Vlo) {
    const int n = blockIdx.x * 64 + (threadIdx.x & 63);
    const int h = threadIdx.x >> 6;
    const float* row = XW + (size_t)n * HF + h * F;

    float v[F];
#pragma unroll
    for (int k4 = 0; k4 < 16; ++k4) {
        float4 x = *(const float4*)(row + k4 * 4);
        v[k4 * 4 + 0] = x.x; v[k4 * 4 + 1] = x.y;
        v[k4 * 4 + 2] = x.z; v[k4 * 4 + 3] = x.w;
    }
    const float* as = a_src + h * F;   // wave-uniform -> scalar loads
    const float* ad = a_dst + h * F;
    float s1 = 0.f, s2 = 0.f;
#pragma unroll
    for (int k = 0; k < F; ++k) { s1 += v[k] * as[k]; s2 += v[k] * ad[k]; }
    f1h[h * NN + n] = s1 * LOG2E;
    f2h[h * NN + n] = s2 * LOG2E;

    // bf16-split transposed copy: V{hi,lo}[h*F+k][n] (coalesced 2B over n)
#pragma unroll
    for (int k = 0; k < F; ++k) {
        __hip_bfloat16 hb = __float2bfloat16(v[k]);
        float hf_ = __bfloat162float(hb);
        __hip_bfloat16 lb = __float2bfloat16(v[k] - hf_);
        Vhi[(size_t)(h * F + k) * NN + n] = hb;
        Vlo[(size_t)(h * F + k) * NN + n] = lb;
    }
}

// ---------------- K3: MFMA fused attention (partials) ----------------
// grid (128, 4): ib = 32-row block, jb = 1024-col block. wave w = head w;
// all 4 waves cover the same j range -> disjoint output columns, no race.
__global__ __launch_bounds__(256) void gat_attn_mfma(
        const int* __restrict__ A, const __hip_bfloat16* __restrict__ Vhi,
        const __hip_bfloat16* __restrict__ Vlo,
        const float* __restrict__ f1h, const float* __restrict__ f2h,
        float* __restrict__ pacc, float* __restrict__ plsum) {
    const int ib = blockIdx.x, jb = blockIdx.y;
    const int h    = threadIdx.x >> 6;
    const int lane = threadIdx.x & 63;
    const int il = lane & 15;        // MFMA row (A) / col (B, C/D)
    const int kg = lane >> 4;        // k-group
    const int i0 = ib * 32 + il;     // rowtile 0
    const int i1 = i0 + 16;          // rowtile 1

    const float c0 = f1h[h * NN + i0];
    const float c1 = f1h[h * NN + i1];

    f32x4 acc0[4], acc1[4], lac0, lac1;
#pragma unroll
    for (int ft = 0; ft < 4; ++ft) {
        acc0[ft] = (f32x4){0.f, 0.f, 0.f, 0.f};
        acc1[ft] = (f32x4){0.f, 0.f, 0.f, 0.f};
    }
    lac0 = (f32x4){0.f, 0.f, 0.f, 0.f};
    lac1 = (f32x4){0.f, 0.f, 0.f, 0.f};

    short8 ones;
#pragma unroll
    for (int e = 0; e < 8; ++e) ones[e] = (short)0x3F80;   // bf16 1.0

    for (int cc = 0; cc < 32; ++cc) {
        const int jl = jb * 1024 + cc * 32 + kg * 8;   // this lane's 8 k's

        const int4* ap0 = (const int4*)(A + (size_t)i0 * NN + jl);
        const int4* ap1 = (const int4*)(A + (size_t)i1 * NN + jl);
        int4 a00 = ap0[0], a01 = ap0[1];
        int4 a10 = ap1[0], a11 = ap1[1];
        int av0[8] = {a00.x, a00.y, a00.z, a00.w, a01.x, a01.y, a01.z, a01.w};
        int av1[8] = {a10.x, a10.y, a10.z, a10.w, a11.x, a11.y, a11.z, a11.w};

        float4 g0 = *(const float4*)(f2h + (size_t)h * NN + jl);
        float4 g1 = *(const float4*)(f2h + (size_t)h * NN + jl + 4);
        float gv[8] = {g0.x, g0.y, g0.z, g0.w, g1.x, g1.y, g1.z, g1.w};

        short8 p0h, p0l, p1h, p1l;
#pragma unroll
        for (int e = 0; e < 8; ++e) {
            float s0 = c0 + gv[e];
            s0 = fmaxf(s0, 0.2f * s0);            // leaky relu (x log2e commutes)
            float p0 = exp2f(s0);                 // no max-sub: bounded
            p0 = (av0[e] != 0) ? p0 : 0.f;
            __hip_bfloat16 h0 = __float2bfloat16(p0);
            __hip_bfloat16 l0 = __float2bfloat16(p0 - __bfloat162float(h0));
            p0h[e] = __builtin_bit_cast(short, h0);
            p0l[e] = __builtin_bit_cast(short, l0);

            float s1 = c1 + gv[e];
            s1 = fmaxf(s1, 0.2f * s1);
            float p1 = exp2f(s1);
            p1 = (av1[e] != 0) ? p1 : 0.f;
            __hip_bfloat16 h1 = __float2bfloat16(p1);
            __hip_bfloat16 l1 = __float2bfloat16(p1 - __bfloat162float(h1));
            p1h[e] = __builtin_bit_cast(short, h1);
            p1l[e] = __builtin_bit_cast(short, l1);
        }

#pragma unroll
        for (int ft = 0; ft < 4; ++ft) {
            const size_t boff = (size_t)(h * F + ft * 16 + il) * NN + jl;
            short8 bh = *reinterpret_cast<const short8*>(Vhi + boff);
            short8 bl = *reinterpret_cast<const short8*>(Vlo + boff);
            acc0[ft] = __builtin_amdgcn_mfma_f32_16x16x32_bf16(p0h, bh, acc0[ft], 0, 0, 0);
            acc0[ft] = __builtin_amdgcn_mfma_f32_16x16x32_bf16(p0h, bl, acc0[ft], 0, 0, 0);
            acc0[ft] = __builtin_amdgcn_mfma_f32_16x16x32_bf16(p0l, bh, acc0[ft], 0, 0, 0);
            acc1[ft] = __builtin_amdgcn_mfma_f32_16x16x32_bf16(p1h, bh, acc1[ft], 0, 0, 0);
            acc1[ft] = __builtin_amdgcn_mfma_f32_16x16x32_bf16(p1h, bl, acc1[ft], 0, 0, 0);
            acc1[ft] = __builtin_amdgcn_mfma_f32_16x16x32_bf16(p1l, bh, acc1[ft], 0, 0, 0);
        }
        lac0 = __builtin_amdgcn_mfma_f32_16x16x32_bf16(p0h, ones, lac0, 0, 0, 0);
        lac0 = __builtin_amdgcn_mfma_f32_16x16x32_bf16(p0l, ones, lac0, 0, 0, 0);
        lac1 = __builtin_amdgcn_mfma_f32_16x16x32_bf16(p1h, ones, lac1, 0, 0, 0);
        lac1 = __builtin_amdgcn_mfma_f32_16x16x32_bf16(p1l, ones, lac1, 0, 0, 0);
    }

    // C/D layout: col = lane&15, row = (lane>>4)*4 + reg
    float* pb = pacc + (size_t)jb * NN * HF + (size_t)(ib * 32) * HF;
#pragma unroll
    for (int ft = 0; ft < 4; ++ft)
#pragma unroll
        for (int r = 0; r < 4; ++r) {
            pb[(kg * 4 + r) * HF + h * F + ft * 16 + il]        = acc0[ft][r];
            pb[(16 + kg * 4 + r) * HF + h * F + ft * 16 + il]   = acc1[ft][r];
        }

    if (il == 0) {   // ones-MFMA: every col holds the row sum; use col 0
#pragma unroll
        for (int r = 0; r < 4; ++r) {
            plsum[(size_t)jb * NN * H + (size_t)(ib * 32 + kg * 4 + r) * H + h]      = lac0[r];
            plsum[(size_t)jb * NN * H + (size_t)(ib * 32 + 16 + kg * 4 + r) * H + h] = lac1[r];
        }
    }
}

// ---------------- K4: combine partials, normalize, ELU ----------------
__global__ __launch_bounds__(256) void finalize(
        const float* __restrict__ pacc, const float* __restrict__ plsum,
        const __hip_bfloat16* __restrict__ Vhi,
        const __hip_bfloat16* __restrict__ Vlo, float* __restrict__ out) {
    const int gid = blockIdx.x * 256 + threadIdx.x;   // 0 .. NN*HF-1
    const int i = gid >> 8, hf = gid & 255, h = hf >> 6;
    float a = 0.f, l = 0.f;
#pragma unroll
    for (int jb = 0; jb < 4; ++jb) {
        a += pacc[(size_t)jb * NN * HF + gid];
        l += plsum[(size_t)jb * NN * H + (size_t)i * H + h];
    }
    if (l == 0.f) {   // empty row: reference softmax degenerates to uniform
        float s = 0.f;
        const __hip_bfloat16* ch = Vhi + (size_t)hf * NN;
        const __hip_bfloat16* cl = Vlo + (size_t)hf * NN;
        for (int j = 0; j < NN; ++j)
            s += __bfloat162float(ch[j]) + __bfloat162float(cl[j]);
        a = s; l = (float)NN;
    }
    float o = a / l;
    out[gid] = (o > 0.f) ? o : (exp2f(o * LOG2E) - 1.f);
}

// ---------------- launch ----------------
extern "C" void kernel_launch(void* const* d_in, const int* in_sizes, int n_in,
                              void* d_out, int out_size, void* d_ws, size_t ws_size,
                              hipStream_t stream) {
    const float* X     = (const float*)d_in[0];
    const int*   A     = (const int*)d_in[1];
    const float* W     = (const float*)d_in[2];
    const float* a_src = (const float*)d_in[3];
    const float* a_dst = (const float*)d_in[4];
    float* out = (float*)d_out;

    // ws: pacc 16MB (XW f32 aliases its first 4MB; dead after K2, K3 clobbers)
    //     | f1h 64KB | f2h 64KB | Vhi 2MB | Vlo 2MB | plsum 256KB = 20.75MB
    float* pacc = (float*)d_ws;
    float* XW   = (float*)d_ws;                 // alias, dead after K2
    float* f1h  = pacc + (size_t)4 * NN * HF;
    float* f2h  = f1h + (size_t)NN * H;
    __hip_bfloat16* Vhi = (__hip_bfloat16*)(f2h + (size_t)NN * H);
    __hip_bfloat16* Vlo = Vhi + (size_t)HF * NN;
    float* plsum = (float*)(Vlo + (size_t)HF * NN);

    gemm_xw<<<dim3(64, 4), 256, 0, stream>>>(X, W, XW);
    scores_transpose<<<64, 256, 0, stream>>>(XW, a_src, a_dst, f1h, f2h, Vhi, Vlo);
    gat_attn_mfma<<<dim3(128, 4), 256, 0, stream>>>(A, Vhi, Vlo, f1h, f2h, pacc, plsum);
    finalize<<<NN * HF / 256, 256, 0, stream>>>(pacc, plsum, Vhi, Vlo, out);
}